// Round 7
// baseline (360.183 us; speedup 1.0000x reference)
//
#include <hip/hip_runtime.h>
#include <hip/hip_bf16.h>

#define N_TOK  16384   // B*H*W
#define KCODES 2048
#define CDIM   128
#define BM     64
#define TPB    512     // 8 waves: 4 compute + 4 fill
#define NCW    4
#define CPW    (KCODES / NCW)   // 512 codes per compute wave
#define TPW    (CPW / 16)       // 32 tiles per compute wave
#define CAP    48
#define DELTA  5.0f    // bf16 d2 error bound ~1.05; 5x margin (validated R4/R5)
#define ASTR   68

typedef __attribute__((ext_vector_type(8))) short bhalf8;
typedef __attribute__((ext_vector_type(4))) float facc4;
typedef __attribute__((ext_vector_type(4))) float nf4;   // clang vector: OK for nontemporal builtin

// ---- prep: codebook fp32 -> bf16 MFMA-frag-tiled layout + ||w||^2 ----
// element (16B) index = T*256 + kf*64 + (q*16 + r): code T*16+r, dims [kf*32+q*8, +8)
__global__ __launch_bounds__(256) void prep_kernel(const float* __restrict__ cb,
                                                   bhalf8* __restrict__ cbt,
                                                   float* __restrict__ wsq) {
    const int T   = blockIdx.x;
    const int tid = threadIdx.x;
    const int r   = tid >> 4;
    const int g   = tid & 15;
    const float4* src = (const float4*)(cb + ((size_t)(T * 16 + r)) * CDIM + g * 8);
    float4 a0 = src[0], a1 = src[1];

    float s = a0.x*a0.x + a0.y*a0.y + a0.z*a0.z + a0.w*a0.w
            + a1.x*a1.x + a1.y*a1.y + a1.z*a1.z + a1.w*a1.w;
    s += __shfl_xor(s, 1, 64);
    s += __shfl_xor(s, 2, 64);
    s += __shfl_xor(s, 4, 64);
    s += __shfl_xor(s, 8, 64);
    if (g == 0) wsq[T * 16 + r] = s;

    union { unsigned u[4]; bhalf8 v; } fu;
    __hip_bfloat162 h0 = __float22bfloat162_rn(make_float2(a0.x, a0.y));
    __hip_bfloat162 h1 = __float22bfloat162_rn(make_float2(a0.z, a0.w));
    __hip_bfloat162 h2 = __float22bfloat162_rn(make_float2(a1.x, a1.y));
    __hip_bfloat162 h3 = __float22bfloat162_rn(make_float2(a1.z, a1.w));
    fu.u[0] = *(unsigned*)&h0; fu.u[1] = *(unsigned*)&h1;
    fu.u[2] = *(unsigned*)&h2; fu.u[3] = *(unsigned*)&h3;
    const int kf = g >> 2, q = g & 3;
    cbt[(size_t)T * 256 + kf * 64 + q * 16 + r] = fu.v;
}

// ---- main: fully-async roles; compute-only LDS spin barriers ----
__global__ __launch_bounds__(TPB, 1) void argmin_kernel(const float* __restrict__ x,
                                                        const float* __restrict__ cb,
                                                        const bhalf8* __restrict__ cbt,
                                                        const float* __restrict__ wsqg,
                                                        float* __restrict__ enc,
                                                        float* __restrict__ quant) {
    __shared__ float As[CDIM][ASTR];     // 34.8 KB exact fp32 x, c-major
    __shared__ float wsqs[KCODES];       // 8 KB
    __shared__ float redvw[NCW][BM];
    __shared__ int   cnt[BM];
    __shared__ int   candk[BM][CAP];     // 12 KB
    __shared__ float candd[BM][CAP];     // 12 KB
    __shared__ int   rowidx[BM];
    __shared__ int   cflag0, cflag1, cflag2, rflag;

    const int tid  = threadIdx.x;
    const int lane = tid & 63;
    const int w    = tid >> 6;
    const int q    = lane >> 4;
    const int r    = lane & 15;
    const int n0   = blockIdx.x * BM;    // 1024 % 64 == 0: single batch
    const int b    = n0 >> 10;
    const int hw0  = n0 & 1023;

    if (tid < BM) cnt[tid] = 0;
    if (tid == 0) { cflag0 = 0; cflag1 = 0; cflag2 = 0; rflag = 0; }
    __syncthreads();   // the ONLY full-block barrier

    if (w >= NCW) {
        // ================= FILL WAVES: zeros -> spin -> ones =================
        const int f = w - NCW;
        nf4* dst = (nf4*)(enc + (size_t)(n0 + f * 16) * KCODES);
        const nf4 z4 = {0.f, 0.f, 0.f, 0.f};
        #pragma unroll 8
        for (int i = 0; i < 128; i++)
            __builtin_nontemporal_store(z4, dst + (size_t)i * 64 + lane);
        __threadfence();                           // drain zero stream
        while (*(volatile int*)&rflag < NCW) __builtin_amdgcn_s_sleep(2);
        __threadfence_block();
        if (lane < 16) {
            int m = f * 16 + lane;
            enc[(size_t)(n0 + m) * KCODES + rowidx[m]] = 1.0f;
        }
        return;
    }

    // ===================== COMPUTE WAVES (tid < 256) ========================
    {   // stage As (coalesced float4 over hw) + wsqs, by 256 threads
        int m4 = (tid & 15) << 2;
        int c0 = tid >> 4;               // 0..15
        #pragma unroll
        for (int i = 0; i < 8; i++) {
            int c = c0 + 16 * i;
            float4 v = *(const float4*)(x + (((size_t)(b * CDIM + c)) << 10) + hw0 + m4);
            *(float4*)(&As[c][m4]) = v;
        }
        #pragma unroll
        for (int i = 0; i < 8; i++) wsqs[i * 256 + tid] = wsqg[i * 256 + tid];
    }
    __threadfence_block();
    if (lane == 0) atomicAdd(&cflag0, 1);
    while (*(volatile int*)&cflag0 < NCW) __builtin_amdgcn_s_sleep(1);
    __threadfence_block();

    // A-frags in registers: A[m=lane&15][k=q*8+j] (verified R3-R5)
    bhalf8 af[4][4];
    #pragma unroll
    for (int rt = 0; rt < 4; rt++) {
        int m = rt * 16 + r;
        #pragma unroll
        for (int kf = 0; kf < 4; kf++) {
            union { unsigned u[4]; bhalf8 v; } fu;
            #pragma unroll
            for (int p = 0; p < 4; p++) {
                int k = kf * 32 + q * 8 + 2 * p;
                __hip_bfloat162 h = __float22bfloat162_rn(make_float2(As[k][m], As[k + 1][m]));
                fu.u[p] = *(unsigned*)&h;
            }
            af[rt][kf] = fu.v;
        }
    }

    const int    cw  = w * CPW;
    const size_t tb0 = (size_t)(cw >> 4) * 256;

    // ---------------- sweep 1: approx min, depth-4 prefetch ----------------
    float rmin[16];
    #pragma unroll
    for (int t = 0; t < 16; t++) rmin[t] = 3.0e38f;
    {
        bhalf8 bb[4][4];
        #pragma unroll
        for (int d = 0; d < 4; d++)
            #pragma unroll
            for (int kf = 0; kf < 4; kf++)
                bb[d][kf] = cbt[tb0 + (size_t)d * 256 + kf * 64 + lane];
        #pragma unroll
        for (int t = 0; t < TPW; t++) {
            facc4 acc[4];
            #pragma unroll
            for (int rt = 0; rt < 4; rt++) acc[rt] = (facc4){0.f, 0.f, 0.f, 0.f};
            #pragma unroll
            for (int kf = 0; kf < 4; kf++)
                #pragma unroll
                for (int rt = 0; rt < 4; rt++)
                    acc[rt] = __builtin_amdgcn_mfma_f32_16x16x32_bf16(af[rt][kf], bb[t & 3][kf], acc[rt], 0, 0, 0);
            float wv = wsqs[cw + t * 16 + r];
            #pragma unroll
            for (int rt = 0; rt < 4; rt++)
                #pragma unroll
                for (int i = 0; i < 4; i++)
                    rmin[rt * 4 + i] = fminf(rmin[rt * 4 + i], fmaf(-2.f, acc[rt][i], wv));
            if (t + 4 < TPW) {
                #pragma unroll
                for (int kf = 0; kf < 4; kf++)
                    bb[t & 3][kf] = cbt[tb0 + (size_t)(t + 4) * 256 + kf * 64 + lane];
            }
        }
    }
    #pragma unroll
    for (int t = 0; t < 16; t++) {
        float v = rmin[t];
        v = fminf(v, __shfl_xor(v, 1, 64));
        v = fminf(v, __shfl_xor(v, 2, 64));
        v = fminf(v, __shfl_xor(v, 4, 64));
        v = fminf(v, __shfl_xor(v, 8, 64));
        if (r == 0) redvw[w][(t >> 2) * 16 + q * 4 + (t & 3)] = v;
    }
    __threadfence_block();
    if (lane == 0) atomicAdd(&cflag1, 1);
    while (*(volatile int*)&cflag1 < NCW) __builtin_amdgcn_s_sleep(1);
    __threadfence_block();

    float thr[16];
    #pragma unroll
    for (int t = 0; t < 16; t++) {
        int rm = (t >> 2) * 16 + q * 4 + (t & 3);
        thr[t] = fminf(fminf(redvw[0][rm], redvw[1][rm]),
                       fminf(redvw[2][rm], redvw[3][rm])) + DELTA;
    }

    // ---------------- sweep 2: bitwise-identical, collect candidates --------
    {
        bhalf8 bb[4][4];
        #pragma unroll
        for (int d = 0; d < 4; d++)
            #pragma unroll
            for (int kf = 0; kf < 4; kf++)
                bb[d][kf] = cbt[tb0 + (size_t)d * 256 + kf * 64 + lane];
        #pragma unroll
        for (int t = 0; t < TPW; t++) {
            facc4 acc[4];
            #pragma unroll
            for (int rt = 0; rt < 4; rt++) acc[rt] = (facc4){0.f, 0.f, 0.f, 0.f};
            #pragma unroll
            for (int kf = 0; kf < 4; kf++)
                #pragma unroll
                for (int rt = 0; rt < 4; rt++)
                    acc[rt] = __builtin_amdgcn_mfma_f32_16x16x32_bf16(af[rt][kf], bb[t & 3][kf], acc[rt], 0, 0, 0);
            float wv = wsqs[cw + t * 16 + r];
            #pragma unroll
            for (int rt = 0; rt < 4; rt++)
                #pragma unroll
                for (int i = 0; i < 4; i++) {
                    float d = fmaf(-2.f, acc[rt][i], wv);
                    if (d <= thr[rt * 4 + i]) {
                        int row = rt * 16 + q * 4 + i;
                        int p = atomicAdd(&cnt[row], 1);
                        if (p < CAP) candk[row][p] = cw + t * 16 + r;
                    }
                }
            if (t + 4 < TPW) {
                #pragma unroll
                for (int kf = 0; kf < 4; kf++)
                    bb[t & 3][kf] = cbt[tb0 + (size_t)(t + 4) * 256 + kf * 64 + lane];
            }
        }
    }
    __threadfence_block();
    if (lane == 0) atomicAdd(&cflag2, 1);
    while (*(volatile int*)&cflag2 < NCW) __builtin_amdgcn_s_sleep(1);
    __threadfence_block();

    // ---------------- rescore: candidate-per-lane exact fp32 ----------------
    const int m0 = 16 * w;               // wave's 16 rows
    int cnts[16], offs[16], tot = 0;
    #pragma unroll
    for (int j = 0; j < 16; j++) {
        int c = min(cnt[m0 + j], CAP);
        offs[j] = tot; tot += c; cnts[j] = c;
    }
    for (int base = 0; base < tot; base += 64) {
        int ci = base + lane;
        if (ci < tot) {
            int j = 0;
            #pragma unroll
            for (int jj = 1; jj < 16; jj++) if (ci >= offs[jj]) j = jj;
            int row  = m0 + j;
            int slot = ci - offs[j];
            int k    = candk[row][slot];
            const float4* cr = (const float4*)(cb + (size_t)k * CDIM);
            float s = 0.f;
            #pragma unroll
            for (int c4 = 0; c4 < 32; c4++) {
                float4 v = cr[c4];
                s = fmaf(As[4 * c4 + 0][row], v.x, s);
                s = fmaf(As[4 * c4 + 1][row], v.y, s);
                s = fmaf(As[4 * c4 + 2][row], v.z, s);
                s = fmaf(As[4 * c4 + 3][row], v.w, s);
            }
            candd[row][slot] = fmaf(-2.f, s, wsqs[k]);
        }
    }
    // LDS writes by own wave: ensure visible to the picking lanes
    __threadfence_block();
    if (lane < 16) {
        int row = m0 + lane;
        float bv = 3.0e38f; int bk = 0x7fffffff;
        for (int t = 0; t < cnts[lane]; t++) {
            float d = candd[row][t];
            int   k = candk[row][t];
            if (d < bv || (d == bv && k < bk)) { bv = d; bk = k; }
        }
        rowidx[row] = bk;
    }
    __threadfence_block();
    if (lane == 0) atomicAdd(&rflag, 1);   // releases fill waves to write ones

    // ---------------- quantized NCHW for this wave's 16 rows ----------------
    #pragma unroll
    for (int i = 0; i < 8; i++) {
        int c  = i * 16 + (lane >> 2);
        int f4 = lane & 3;
        int mb = m0 + 4 * f4;
        float4 v;
        v.x = cb[(size_t)rowidx[mb + 0] * CDIM + c];
        v.y = cb[(size_t)rowidx[mb + 1] * CDIM + c];
        v.z = cb[(size_t)rowidx[mb + 2] * CDIM + c];
        v.w = cb[(size_t)rowidx[mb + 3] * CDIM + c];
        *(float4*)(quant + (((size_t)(b * CDIM + c)) << 10) + hw0 + mb) = v;
    }
}

extern "C" void kernel_launch(void* const* d_in, const int* in_sizes, int n_in,
                              void* d_out, int out_size, void* d_ws, size_t ws_size,
                              hipStream_t stream) {
    const float* x  = (const float*)d_in[0];   // [16,128,32,32] f32
    const float* cb = (const float*)d_in[1];   // [2048,128] f32
    float* out = (float*)d_out;                // encodings [N,K] then quantized

    bhalf8* cbt  = (bhalf8*)d_ws;                      // 512 KB tiled bf16
    float*  wsqp = (float*)((char*)d_ws + 512 * 1024); // 8 KB

    prep_kernel<<<KCODES / 16, 256, 0, stream>>>(cb, cbt, wsqp);
    argmin_kernel<<<N_TOK / BM, TPB, 0, stream>>>(x, cb, cbt, wsqp,
                                                  out, out + (size_t)N_TOK * KCODES);
}

// Round 8
// 357.352 us; speedup vs baseline: 1.0079x; 1.0079x over previous
//
#include <hip/hip_runtime.h>
#include <hip/hip_bf16.h>

#define N_TOK  16384   // B*H*W
#define KCODES 2048
#define CDIM   128
#define BM     64
#define TPB    512     // 8 waves: 4 compute + 4 fill
#define NCW    4
#define CPW    (KCODES / NCW)   // 512 codes per compute wave
#define TPW    (CPW / 16)       // 32 tiles per compute wave
#define CAP    48
#define DELTA  5.0f    // bf16 d2 error bound ~1.05; 5x margin (validated R4-R7)
#define ASTR   68

typedef __attribute__((ext_vector_type(8))) short bhalf8;
typedef __attribute__((ext_vector_type(4))) float facc4;

// ---- prep: codebook fp32 -> bf16 MFMA-frag-tiled layout + ||w||^2 ----
// element (16B) index = T*256 + kf*64 + (q*16 + r): code T*16+r, dims [kf*32+q*8, +8)
__global__ __launch_bounds__(256) void prep_kernel(const float* __restrict__ cb,
                                                   bhalf8* __restrict__ cbt,
                                                   float* __restrict__ wsq) {
    const int T   = blockIdx.x;
    const int tid = threadIdx.x;
    const int r   = tid >> 4;
    const int g   = tid & 15;
    const float4* src = (const float4*)(cb + ((size_t)(T * 16 + r)) * CDIM + g * 8);
    float4 a0 = src[0], a1 = src[1];

    float s = a0.x*a0.x + a0.y*a0.y + a0.z*a0.z + a0.w*a0.w
            + a1.x*a1.x + a1.y*a1.y + a1.z*a1.z + a1.w*a1.w;
    s += __shfl_xor(s, 1, 64);
    s += __shfl_xor(s, 2, 64);
    s += __shfl_xor(s, 4, 64);
    s += __shfl_xor(s, 8, 64);
    if (g == 0) wsq[T * 16 + r] = s;

    union { unsigned u[4]; bhalf8 v; } fu;
    __hip_bfloat162 h0 = __float22bfloat162_rn(make_float2(a0.x, a0.y));
    __hip_bfloat162 h1 = __float22bfloat162_rn(make_float2(a0.z, a0.w));
    __hip_bfloat162 h2 = __float22bfloat162_rn(make_float2(a1.x, a1.y));
    __hip_bfloat162 h3 = __float22bfloat162_rn(make_float2(a1.z, a1.w));
    fu.u[0] = *(unsigned*)&h0; fu.u[1] = *(unsigned*)&h1;
    fu.u[2] = *(unsigned*)&h2; fu.u[3] = *(unsigned*)&h3;
    const int kf = g >> 2, q = g & 3;
    cbt[(size_t)T * 256 + kf * 64 + q * 16 + r] = fu.v;
}

// ---- main: fully-async roles; compute-only LDS spin barriers ----
// NOTE (R7 lesson): zero-fill MUST go through L2 (normal stores) — L2 is the
// write-combiner on CDNA; `nt` stores caused +134MB HBM RMW (FETCH 132MB).
__global__ __launch_bounds__(TPB, 1) void argmin_kernel(const float* __restrict__ x,
                                                        const float* __restrict__ cb,
                                                        const bhalf8* __restrict__ cbt,
                                                        const float* __restrict__ wsqg,
                                                        float* __restrict__ enc,
                                                        float* __restrict__ quant) {
    __shared__ float As[CDIM][ASTR];     // 34.8 KB exact fp32 x, c-major
    __shared__ float wsqs[KCODES];       // 8 KB
    __shared__ float redvw[NCW][BM];
    __shared__ int   cnt[BM];
    __shared__ int   candk[BM][CAP];     // 12 KB
    __shared__ float candd[BM][CAP];     // 12 KB
    __shared__ int   rowidx[BM];
    __shared__ int   cflag0, cflag1, cflag2, rflag;

    const int tid  = threadIdx.x;
    const int lane = tid & 63;
    const int w    = tid >> 6;
    const int q    = lane >> 4;
    const int r    = lane & 15;
    const int n0   = blockIdx.x * BM;    // 1024 % 64 == 0: single batch
    const int b    = n0 >> 10;
    const int hw0  = n0 & 1023;

    if (tid < BM) cnt[tid] = 0;
    if (tid == 0) { cflag0 = 0; cflag1 = 0; cflag2 = 0; rflag = 0; }
    __syncthreads();   // the ONLY full-block barrier

    if (w >= NCW) {
        // ===== FILL WAVES: dense zero stream (through L2) -> spin -> ones =====
        const int f = w - NCW;
        float4* dst = (float4*)(enc + (size_t)(n0 + f * 16) * KCODES);
        const float4 z4 = {0.f, 0.f, 0.f, 0.f};
        #pragma unroll 8
        for (int i = 0; i < 128; i++)
            dst[(size_t)i * 64 + lane] = z4;
        __threadfence();                           // drain zero stream (vmcnt)
        while (*(volatile int*)&rflag < NCW) __builtin_amdgcn_s_sleep(2);
        __threadfence_block();
        if (lane < 16) {
            int m = f * 16 + lane;
            enc[(size_t)(n0 + m) * KCODES + rowidx[m]] = 1.0f;
        }
        return;
    }

    // ===================== COMPUTE WAVES (tid < 256) ========================
    {   // stage As (coalesced float4 over hw) + wsqs, by 256 threads
        int m4 = (tid & 15) << 2;
        int c0 = tid >> 4;               // 0..15
        #pragma unroll
        for (int i = 0; i < 8; i++) {
            int c = c0 + 16 * i;
            float4 v = *(const float4*)(x + (((size_t)(b * CDIM + c)) << 10) + hw0 + m4);
            *(float4*)(&As[c][m4]) = v;
        }
        #pragma unroll
        for (int i = 0; i < 8; i++) wsqs[i * 256 + tid] = wsqg[i * 256 + tid];
    }
    __threadfence_block();
    if (lane == 0) atomicAdd(&cflag0, 1);
    while (*(volatile int*)&cflag0 < NCW) __builtin_amdgcn_s_sleep(1);
    __threadfence_block();

    // A-frags in registers: A[m=lane&15][k=q*8+j] (verified R3-R7)
    bhalf8 af[4][4];
    #pragma unroll
    for (int rt = 0; rt < 4; rt++) {
        int m = rt * 16 + r;
        #pragma unroll
        for (int kf = 0; kf < 4; kf++) {
            union { unsigned u[4]; bhalf8 v; } fu;
            #pragma unroll
            for (int p = 0; p < 4; p++) {
                int k = kf * 32 + q * 8 + 2 * p;
                __hip_bfloat162 h = __float22bfloat162_rn(make_float2(As[k][m], As[k + 1][m]));
                fu.u[p] = *(unsigned*)&h;
            }
            af[rt][kf] = fu.v;
        }
    }

    const int    cw  = w * CPW;
    const size_t tb0 = (size_t)(cw >> 4) * 256;

    // ---------------- sweep 1: approx min, depth-4 prefetch ----------------
    float rmin[16];
    #pragma unroll
    for (int t = 0; t < 16; t++) rmin[t] = 3.0e38f;
    {
        bhalf8 bb[4][4];
        #pragma unroll
        for (int d = 0; d < 4; d++)
            #pragma unroll
            for (int kf = 0; kf < 4; kf++)
                bb[d][kf] = cbt[tb0 + (size_t)d * 256 + kf * 64 + lane];
        #pragma unroll
        for (int t = 0; t < TPW; t++) {
            facc4 acc[4];
            #pragma unroll
            for (int rt = 0; rt < 4; rt++) acc[rt] = (facc4){0.f, 0.f, 0.f, 0.f};
            #pragma unroll
            for (int kf = 0; kf < 4; kf++)
                #pragma unroll
                for (int rt = 0; rt < 4; rt++)
                    acc[rt] = __builtin_amdgcn_mfma_f32_16x16x32_bf16(af[rt][kf], bb[t & 3][kf], acc[rt], 0, 0, 0);
            float wv = wsqs[cw + t * 16 + r];
            #pragma unroll
            for (int rt = 0; rt < 4; rt++)
                #pragma unroll
                for (int i = 0; i < 4; i++)
                    rmin[rt * 4 + i] = fminf(rmin[rt * 4 + i], fmaf(-2.f, acc[rt][i], wv));
            if (t + 4 < TPW) {
                #pragma unroll
                for (int kf = 0; kf < 4; kf++)
                    bb[t & 3][kf] = cbt[tb0 + (size_t)(t + 4) * 256 + kf * 64 + lane];
            }
        }
    }
    #pragma unroll
    for (int t = 0; t < 16; t++) {
        float v = rmin[t];
        v = fminf(v, __shfl_xor(v, 1, 64));
        v = fminf(v, __shfl_xor(v, 2, 64));
        v = fminf(v, __shfl_xor(v, 4, 64));
        v = fminf(v, __shfl_xor(v, 8, 64));
        if (r == 0) redvw[w][(t >> 2) * 16 + q * 4 + (t & 3)] = v;
    }
    __threadfence_block();
    if (lane == 0) atomicAdd(&cflag1, 1);
    while (*(volatile int*)&cflag1 < NCW) __builtin_amdgcn_s_sleep(1);
    __threadfence_block();

    float thr[16];
    #pragma unroll
    for (int t = 0; t < 16; t++) {
        int rm = (t >> 2) * 16 + q * 4 + (t & 3);
        thr[t] = fminf(fminf(redvw[0][rm], redvw[1][rm]),
                       fminf(redvw[2][rm], redvw[3][rm])) + DELTA;
    }

    // ---------------- sweep 2: bitwise-identical, collect candidates --------
    {
        bhalf8 bb[4][4];
        #pragma unroll
        for (int d = 0; d < 4; d++)
            #pragma unroll
            for (int kf = 0; kf < 4; kf++)
                bb[d][kf] = cbt[tb0 + (size_t)d * 256 + kf * 64 + lane];
        #pragma unroll
        for (int t = 0; t < TPW; t++) {
            facc4 acc[4];
            #pragma unroll
            for (int rt = 0; rt < 4; rt++) acc[rt] = (facc4){0.f, 0.f, 0.f, 0.f};
            #pragma unroll
            for (int kf = 0; kf < 4; kf++)
                #pragma unroll
                for (int rt = 0; rt < 4; rt++)
                    acc[rt] = __builtin_amdgcn_mfma_f32_16x16x32_bf16(af[rt][kf], bb[t & 3][kf], acc[rt], 0, 0, 0);
            float wv = wsqs[cw + t * 16 + r];
            #pragma unroll
            for (int rt = 0; rt < 4; rt++)
                #pragma unroll
                for (int i = 0; i < 4; i++) {
                    float d = fmaf(-2.f, acc[rt][i], wv);
                    if (d <= thr[rt * 4 + i]) {
                        int row = rt * 16 + q * 4 + i;
                        int p = atomicAdd(&cnt[row], 1);
                        if (p < CAP) candk[row][p] = cw + t * 16 + r;
                    }
                }
            if (t + 4 < TPW) {
                #pragma unroll
                for (int kf = 0; kf < 4; kf++)
                    bb[t & 3][kf] = cbt[tb0 + (size_t)(t + 4) * 256 + kf * 64 + lane];
            }
        }
    }
    __threadfence_block();
    if (lane == 0) atomicAdd(&cflag2, 1);
    while (*(volatile int*)&cflag2 < NCW) __builtin_amdgcn_s_sleep(1);
    __threadfence_block();

    // ---------------- rescore: candidate-per-lane exact fp32 ----------------
    const int m0 = 16 * w;               // wave's 16 rows
    int cnts[16], offs[16], tot = 0;
    #pragma unroll
    for (int j = 0; j < 16; j++) {
        int c = min(cnt[m0 + j], CAP);
        offs[j] = tot; tot += c; cnts[j] = c;
    }
    for (int base = 0; base < tot; base += 64) {
        int ci = base + lane;
        if (ci < tot) {
            int j = 0;
            #pragma unroll
            for (int jj = 1; jj < 16; jj++) if (ci >= offs[jj]) j = jj;
            int row  = m0 + j;
            int slot = ci - offs[j];
            int k    = candk[row][slot];
            const float4* cr = (const float4*)(cb + (size_t)k * CDIM);
            float s = 0.f;
            #pragma unroll
            for (int c4 = 0; c4 < 32; c4++) {
                float4 v = cr[c4];
                s = fmaf(As[4 * c4 + 0][row], v.x, s);
                s = fmaf(As[4 * c4 + 1][row], v.y, s);
                s = fmaf(As[4 * c4 + 2][row], v.z, s);
                s = fmaf(As[4 * c4 + 3][row], v.w, s);
            }
            candd[row][slot] = fmaf(-2.f, s, wsqs[k]);
        }
    }
    // LDS writes by own wave: ensure visible to the picking lanes
    __threadfence_block();
    if (lane < 16) {
        int row = m0 + lane;
        float bv = 3.0e38f; int bk = 0x7fffffff;
        for (int t = 0; t < cnts[lane]; t++) {
            float d = candd[row][t];
            int   k = candk[row][t];
            if (d < bv || (d == bv && k < bk)) { bv = d; bk = k; }
        }
        rowidx[row] = bk;
    }
    __threadfence_block();
    if (lane == 0) atomicAdd(&rflag, 1);   // releases fill waves to write ones

    // ---------------- quantized NCHW for this wave's 16 rows ----------------
    #pragma unroll
    for (int i = 0; i < 8; i++) {
        int c  = i * 16 + (lane >> 2);
        int f4 = lane & 3;
        int mb = m0 + 4 * f4;
        float4 v;
        v.x = cb[(size_t)rowidx[mb + 0] * CDIM + c];
        v.y = cb[(size_t)rowidx[mb + 1] * CDIM + c];
        v.z = cb[(size_t)rowidx[mb + 2] * CDIM + c];
        v.w = cb[(size_t)rowidx[mb + 3] * CDIM + c];
        *(float4*)(quant + (((size_t)(b * CDIM + c)) << 10) + hw0 + mb) = v;
    }
}

extern "C" void kernel_launch(void* const* d_in, const int* in_sizes, int n_in,
                              void* d_out, int out_size, void* d_ws, size_t ws_size,
                              hipStream_t stream) {
    const float* x  = (const float*)d_in[0];   // [16,128,32,32] f32
    const float* cb = (const float*)d_in[1];   // [2048,128] f32
    float* out = (float*)d_out;                // encodings [N,K] then quantized

    bhalf8* cbt  = (bhalf8*)d_ws;                      // 512 KB tiled bf16
    float*  wsqp = (float*)((char*)d_ws + 512 * 1024); // 8 KB

    prep_kernel<<<KCODES / 16, 256, 0, stream>>>(cb, cbt, wsqp);
    argmin_kernel<<<N_TOK / BM, TPB, 0, stream>>>(x, cb, cbt, wsqp,
                                                  out, out + (size_t)N_TOK * KCODES);
}

// Round 9
// 211.565 us; speedup vs baseline: 1.7025x; 1.6891x over previous
//
#include <hip/hip_runtime.h>
#include <hip/hip_bf16.h>

#define N_TOK  16384   // B*H*W
#define KCODES 2048
#define CDIM   128
#define BM     64
#define TPB    512     // 8 waves, ALL compute
#define NCW    8
#define CPW    (KCODES / NCW)   // 256 codes per wave
#define TPW    (CPW / 16)       // 16 tiles per wave
#define CAP    48
#define DELTA  5.0f    // bf16 d2 error bound ~1.05; 5x margin (validated R3-R8)
#define ASTR   68

typedef __attribute__((ext_vector_type(8))) short bhalf8;
typedef __attribute__((ext_vector_type(4))) float facc4;

// ---- prep: codebook fp32 -> bf16 MFMA-frag-tiled layout + ||w||^2 ----
// element (16B) index = T*256 + kf*64 + (q*16 + r): code T*16+r, dims [kf*32+q*8, +8)
__global__ __launch_bounds__(256) void prep_kernel(const float* __restrict__ cb,
                                                   bhalf8* __restrict__ cbt,
                                                   float* __restrict__ wsq) {
    const int T   = blockIdx.x;
    const int tid = threadIdx.x;
    const int r   = tid >> 4;
    const int g   = tid & 15;
    const float4* src = (const float4*)(cb + ((size_t)(T * 16 + r)) * CDIM + g * 8);
    float4 a0 = src[0], a1 = src[1];

    float s = a0.x*a0.x + a0.y*a0.y + a0.z*a0.z + a0.w*a0.w
            + a1.x*a1.x + a1.y*a1.y + a1.z*a1.z + a1.w*a1.w;
    s += __shfl_xor(s, 1, 64);
    s += __shfl_xor(s, 2, 64);
    s += __shfl_xor(s, 4, 64);
    s += __shfl_xor(s, 8, 64);
    if (g == 0) wsq[T * 16 + r] = s;

    union { unsigned u[4]; bhalf8 v; } fu;
    __hip_bfloat162 h0 = __float22bfloat162_rn(make_float2(a0.x, a0.y));
    __hip_bfloat162 h1 = __float22bfloat162_rn(make_float2(a0.z, a0.w));
    __hip_bfloat162 h2 = __float22bfloat162_rn(make_float2(a1.x, a1.y));
    __hip_bfloat162 h3 = __float22bfloat162_rn(make_float2(a1.z, a1.w));
    fu.u[0] = *(unsigned*)&h0; fu.u[1] = *(unsigned*)&h1;
    fu.u[2] = *(unsigned*)&h2; fu.u[3] = *(unsigned*)&h3;
    const int kf = g >> 2, q = g & 3;
    cbt[(size_t)T * 256 + kf * 64 + q * 16 + r] = fu.v;
}

// ---- argmin: 8 compute waves, plain barriers, NO enc zero traffic ----
// (R8 lesson: a concurrent 131MB store stream thrashes L2 and triples HBM
//  traffic — zeros are done by hipMemsetAsync BEFORE this kernel.)
__global__ __launch_bounds__(TPB, 1) void argmin_kernel(const float* __restrict__ x,
                                                        const float* __restrict__ cb,
                                                        const bhalf8* __restrict__ cbt,
                                                        const float* __restrict__ wsqg,
                                                        float* __restrict__ enc,
                                                        float* __restrict__ quant) {
    __shared__ float As[CDIM][ASTR];     // 34.8 KB exact fp32 x, c-major
    __shared__ float wsqs[KCODES];       // 8 KB
    __shared__ float redvw[NCW][BM];
    __shared__ int   cnt[BM];
    __shared__ int   candk[BM][CAP];     // 12 KB
    __shared__ float candd[BM][CAP];     // 12 KB
    __shared__ int   rowidx[BM];

    const int tid  = threadIdx.x;
    const int lane = tid & 63;
    const int w    = tid >> 6;           // 8 waves
    const int q    = lane >> 4;
    const int r    = lane & 15;
    const int n0   = blockIdx.x * BM;    // 1024 % 64 == 0: single batch
    const int b    = n0 >> 10;
    const int hw0  = n0 & 1023;

    // ---- stage As (coalesced float4 over hw) + wsqs
    {
        int m4 = (tid & 15) << 2;
        int c0 = tid >> 4;               // 0..31
        #pragma unroll
        for (int i = 0; i < 4; i++) {
            int c = c0 + 32 * i;
            float4 v = *(const float4*)(x + (((size_t)(b * CDIM + c)) << 10) + hw0 + m4);
            *(float4*)(&As[c][m4]) = v;
        }
        #pragma unroll
        for (int i = 0; i < 4; i++) wsqs[i * TPB + tid] = wsqg[i * TPB + tid];
        if (tid < BM) cnt[tid] = 0;
    }
    __syncthreads();

    // ---- A-frags in registers: A[m=lane&15][k=q*8+j] (verified R3-R8)
    bhalf8 af[4][4];
    #pragma unroll
    for (int rt = 0; rt < 4; rt++) {
        int m = rt * 16 + r;
        #pragma unroll
        for (int kf = 0; kf < 4; kf++) {
            union { unsigned u[4]; bhalf8 v; } fu;
            #pragma unroll
            for (int p = 0; p < 4; p++) {
                int k = kf * 32 + q * 8 + 2 * p;
                __hip_bfloat162 h = __float22bfloat162_rn(make_float2(As[k][m], As[k + 1][m]));
                fu.u[p] = *(unsigned*)&h;
            }
            af[rt][kf] = fu.v;
        }
    }

    const int    cw  = w * CPW;
    const size_t tb0 = (size_t)(cw >> 4) * 256;

    // ---------------- sweep 1: approx min, depth-4 prefetch ----------------
    float rmin[16];
    #pragma unroll
    for (int t = 0; t < 16; t++) rmin[t] = 3.0e38f;
    {
        bhalf8 bb[4][4];
        #pragma unroll
        for (int d = 0; d < 4; d++)
            #pragma unroll
            for (int kf = 0; kf < 4; kf++)
                bb[d][kf] = cbt[tb0 + (size_t)d * 256 + kf * 64 + lane];
        #pragma unroll
        for (int t = 0; t < TPW; t++) {
            facc4 acc[4];
            #pragma unroll
            for (int rt = 0; rt < 4; rt++) acc[rt] = (facc4){0.f, 0.f, 0.f, 0.f};
            #pragma unroll
            for (int kf = 0; kf < 4; kf++)
                #pragma unroll
                for (int rt = 0; rt < 4; rt++)
                    acc[rt] = __builtin_amdgcn_mfma_f32_16x16x32_bf16(af[rt][kf], bb[t & 3][kf], acc[rt], 0, 0, 0);
            float wv = wsqs[cw + t * 16 + r];
            #pragma unroll
            for (int rt = 0; rt < 4; rt++)
                #pragma unroll
                for (int i = 0; i < 4; i++)
                    rmin[rt * 4 + i] = fminf(rmin[rt * 4 + i], fmaf(-2.f, acc[rt][i], wv));
            if (t + 4 < TPW) {
                #pragma unroll
                for (int kf = 0; kf < 4; kf++)
                    bb[t & 3][kf] = cbt[tb0 + (size_t)(t + 4) * 256 + kf * 64 + lane];
            }
        }
    }
    #pragma unroll
    for (int t = 0; t < 16; t++) {
        float v = rmin[t];
        v = fminf(v, __shfl_xor(v, 1, 64));
        v = fminf(v, __shfl_xor(v, 2, 64));
        v = fminf(v, __shfl_xor(v, 4, 64));
        v = fminf(v, __shfl_xor(v, 8, 64));
        if (r == 0) redvw[w][(t >> 2) * 16 + q * 4 + (t & 3)] = v;
    }
    __syncthreads();

    float thr[16];
    #pragma unroll
    for (int t = 0; t < 16; t++) {
        int rm = (t >> 2) * 16 + q * 4 + (t & 3);
        float mv = redvw[0][rm];
        #pragma unroll
        for (int i = 1; i < NCW; i++) mv = fminf(mv, redvw[i][rm]);
        thr[t] = mv + DELTA;
    }

    // ---------------- sweep 2: bitwise-identical, collect candidates --------
    {
        bhalf8 bb[4][4];
        #pragma unroll
        for (int d = 0; d < 4; d++)
            #pragma unroll
            for (int kf = 0; kf < 4; kf++)
                bb[d][kf] = cbt[tb0 + (size_t)d * 256 + kf * 64 + lane];
        #pragma unroll
        for (int t = 0; t < TPW; t++) {
            facc4 acc[4];
            #pragma unroll
            for (int rt = 0; rt < 4; rt++) acc[rt] = (facc4){0.f, 0.f, 0.f, 0.f};
            #pragma unroll
            for (int kf = 0; kf < 4; kf++)
                #pragma unroll
                for (int rt = 0; rt < 4; rt++)
                    acc[rt] = __builtin_amdgcn_mfma_f32_16x16x32_bf16(af[rt][kf], bb[t & 3][kf], acc[rt], 0, 0, 0);
            float wv = wsqs[cw + t * 16 + r];
            #pragma unroll
            for (int rt = 0; rt < 4; rt++)
                #pragma unroll
                for (int i = 0; i < 4; i++) {
                    float d = fmaf(-2.f, acc[rt][i], wv);
                    if (d <= thr[rt * 4 + i]) {
                        int row = rt * 16 + q * 4 + i;
                        int p = atomicAdd(&cnt[row], 1);
                        if (p < CAP) candk[row][p] = cw + t * 16 + r;
                    }
                }
            if (t + 4 < TPW) {
                #pragma unroll
                for (int kf = 0; kf < 4; kf++)
                    bb[t & 3][kf] = cbt[tb0 + (size_t)(t + 4) * 256 + kf * 64 + lane];
            }
        }
    }
    __syncthreads();

    // ---------------- rescore: candidate-per-lane exact fp32 ----------------
    const int m0 = 8 * w;                // wave's 8 rows
    int cnts[8], offs[8], tot = 0;
    #pragma unroll
    for (int j = 0; j < 8; j++) {
        int c = min(cnt[m0 + j], CAP);
        offs[j] = tot; tot += c; cnts[j] = c;
    }
    for (int base = 0; base < tot; base += 64) {
        int ci = base + lane;
        if (ci < tot) {
            int j = 0;
            #pragma unroll
            for (int jj = 1; jj < 8; jj++) if (ci >= offs[jj]) j = jj;
            int row  = m0 + j;
            int slot = ci - offs[j];
            int k    = candk[row][slot];
            const float4* cr = (const float4*)(cb + (size_t)k * CDIM);
            float s = 0.f;
            #pragma unroll
            for (int c4 = 0; c4 < 32; c4++) {
                float4 v = cr[c4];
                s = fmaf(As[4 * c4 + 0][row], v.x, s);
                s = fmaf(As[4 * c4 + 1][row], v.y, s);
                s = fmaf(As[4 * c4 + 2][row], v.z, s);
                s = fmaf(As[4 * c4 + 3][row], v.w, s);
            }
            candd[row][slot] = fmaf(-2.f, s, wsqs[k]);
        }
    }
    __threadfence_block();               // own-wave LDS writes -> picking lanes
    if (lane < 8) {
        int row = m0 + lane;
        float bv = 3.0e38f; int bk = 0x7fffffff;
        for (int t = 0; t < cnts[lane]; t++) {
            float d = candd[row][t];
            int   k = candk[row][t];
            if (d < bv || (d == bv && k < bk)) { bv = d; bk = k; }
        }
        rowidx[row] = bk;
    }
    __syncthreads();

    // ---- ones (enc pre-zeroed by memset) ----
    if (tid < BM) enc[(size_t)(n0 + tid) * KCODES + rowidx[tid]] = 1.0f;

    // ---- quantized NCHW, full-line cooperative: 256B contiguous per c ----
    #pragma unroll
    for (int it = 0; it < 4; it++) {
        int i  = it * TPB + tid;         // 0..2047
        int c  = i >> 4;                 // 0..127
        int m4 = (i & 15) << 2;          // 0..60
        float4 v;
        v.x = cb[(size_t)rowidx[m4 + 0] * CDIM + c];
        v.y = cb[(size_t)rowidx[m4 + 1] * CDIM + c];
        v.z = cb[(size_t)rowidx[m4 + 2] * CDIM + c];
        v.w = cb[(size_t)rowidx[m4 + 3] * CDIM + c];
        *(float4*)(quant + (((size_t)(b * CDIM + c)) << 10) + hw0 + m4) = v;
    }
}

extern "C" void kernel_launch(void* const* d_in, const int* in_sizes, int n_in,
                              void* d_out, int out_size, void* d_ws, size_t ws_size,
                              hipStream_t stream) {
    const float* x  = (const float*)d_in[0];   // [16,128,32,32] f32
    const float* cb = (const float*)d_in[1];   // [2048,128] f32
    float* out = (float*)d_out;                // encodings [N,K] then quantized

    bhalf8* cbt  = (bhalf8*)d_ws;                      // 512 KB tiled bf16
    float*  wsqp = (float*)((char*)d_ws + 512 * 1024); // 8 KB

    // dense zero-fill of encodings at memset speed (~6.6 TB/s), isolated from compute
    hipMemsetAsync(out, 0, (size_t)N_TOK * KCODES * sizeof(float), stream);
    prep_kernel<<<KCODES / 16, 256, 0, stream>>>(cb, cbt, wsqp);
    argmin_kernel<<<N_TOK / BM, TPB, 0, stream>>>(x, cb, cbt, wsqp,
                                                  out, out + (size_t)N_TOK * KCODES);
}